// Round 1
// baseline (229.663 us; speedup 1.0000x reference)
//
#include <hip/hip_runtime.h>
#include <cstdint>
#include <cstddef>

// Problem constants
#define BATCH 8
#define CCH   512     // channels
#define SSP   1024    // spatial = 32*32
#define NH    8       // heads
#define DH    64      // head dim
#define O3    1536    // 3*C

typedef __bf16 bf16x8 __attribute__((ext_vector_type(8)));
typedef float  f32x4  __attribute__((ext_vector_type(4)));

__device__ __forceinline__ unsigned short f2bf(float f) {
    unsigned u = __builtin_bit_cast(unsigned, f);
    unsigned r = u + 0x7fffu + ((u >> 16) & 1u);   // RNE
    return (unsigned short)(r >> 16);
}

__device__ __forceinline__ bf16x8 ld8(const unsigned short* p) {
    // 16B load reinterpreted as 8 x bf16 (ds_read_b128 / global_load_dwordx4)
    uint4 u = *(const uint4*)p;
    return __builtin_bit_cast(bf16x8, u);
}

// ---------------------------------------------------------------------------
// fp32 -> bf16 weight conversion (qkv_w, proj_w)
__global__ __launch_bounds__(256) void wconv(const float* __restrict__ src,
                                             unsigned short* __restrict__ dst,
                                             int n4) {
    int i = blockIdx.x * 256 + threadIdx.x;
    if (i < n4) {
        float4 v = ((const float4*)src)[i];
        ushort4 o;
        o.x = f2bf(v.x); o.y = f2bf(v.y); o.z = f2bf(v.z); o.w = f2bf(v.w);
        ((ushort4*)dst)[i] = o;
    }
}

// ---------------------------------------------------------------------------
// GroupNorm (32 groups) + transpose write: xn_t[b][s][c] in bf16.
// One block per (b, group): 16 channels x 1024 spatial = 16384 floats.
__global__ __launch_bounds__(256) void groupnorm_t(const float* __restrict__ x,
                                                   const float* __restrict__ gw,
                                                   const float* __restrict__ gb,
                                                   unsigned short* __restrict__ xnt) {
    int blk = blockIdx.x;
    int b = blk >> 5, g = blk & 31;
    const float4* xp = (const float4*)(x + (size_t)(b * CCH + g * 16) * SSP);
    int t = threadIdx.x;

    float4 vals[16];
    float sum = 0.f, ss = 0.f;
#pragma unroll
    for (int i = 0; i < 16; i++) {
        float4 v = xp[i * 256 + t];
        vals[i] = v;
        sum += (v.x + v.y) + (v.z + v.w);
        ss  += (v.x * v.x + v.y * v.y) + (v.z * v.z + v.w * v.w);
    }
#pragma unroll
    for (int o = 32; o; o >>= 1) {
        sum += __shfl_xor(sum, o, 64);
        ss  += __shfl_xor(ss,  o, 64);
    }
    __shared__ float red[8];
    if ((t & 63) == 0) { red[(t >> 6) * 2] = sum; red[(t >> 6) * 2 + 1] = ss; }
    __syncthreads();
    sum = red[0] + red[2] + red[4] + red[6];
    ss  = red[1] + red[3] + red[5] + red[7];

    float mean = sum * (1.f / 16384.f);
    float var  = ss * (1.f / 16384.f) - mean * mean;
    float rstd = rsqrtf(var + 1e-5f);

    __shared__ unsigned short tile[16][1032];   // bf16, padded row (33 KB)
#pragma unroll
    for (int i = 0; i < 16; i++) {
        int f4 = i * 256 + t;
        int c = f4 >> 8;            // 256 float4 per channel
        int s = (f4 & 255) * 4;
        float wsc = gw[g * 16 + c] * rstd;
        float bia = gb[g * 16 + c] - mean * wsc;
        float4 v = vals[i];
        tile[c][s + 0] = f2bf(v.x * wsc + bia);
        tile[c][s + 1] = f2bf(v.y * wsc + bia);
        tile[c][s + 2] = f2bf(v.z * wsc + bia);
        tile[c][s + 3] = f2bf(v.w * wsc + bia);
    }
    __syncthreads();

    // transposed write: xn_t[(b*S + s)*C + g*16 + c], 2 bf16 (4B) per store
    int c2 = (t & 7) * 2, sr = t >> 3;
    unsigned short* outbase = xnt + (size_t)b * SSP * CCH + g * 16 + c2;
#pragma unroll
    for (int i = 0; i < 32; i++) {
        int s = i * 32 + sr;
        unsigned v = (unsigned)tile[c2][s] | ((unsigned)tile[c2 + 1][s] << 16);
        *(unsigned*)(outbase + (size_t)s * CCH) = v;
    }
}

// ---------------------------------------------------------------------------
// NT GEMM 128x128 tile, 16x16x32 bf16 MFMA, K=512.
// qkv: qkv_t[b][s][o] (bf16) = sum_c xn_t[b][s][c] * qkv_w[o][c] + qkv_b[o]
__global__ __launch_bounds__(256) void gemm_qkv(const unsigned short* __restrict__ Aall,
                                                const unsigned short* __restrict__ Bw,
                                                const float* __restrict__ bias,
                                                unsigned short* __restrict__ Call) {
    const int K = 512;
    int bz = blockIdx.z;
    const unsigned short* A = Aall + (size_t)bz * SSP * CCH;
    unsigned short* Cp = Call + (size_t)bz * SSP * O3;
    int m0 = blockIdx.x * 128, n0 = blockIdx.y * 128;

    __shared__ unsigned short As[128][40], Bs[128][40];  // +8 pad: 2-way banks, 16B rows
    int t = threadIdx.x, wave = t >> 6, lane = t & 63;
    int quad = lane >> 4, l16 = lane & 15;
    int wm = (wave & 1) * 64, wn = (wave >> 1) * 64;

    f32x4 acc[4][4];
#pragma unroll
    for (int i = 0; i < 4; i++)
#pragma unroll
        for (int j = 0; j < 4; j++) acc[i][j] = f32x4{0.f, 0.f, 0.f, 0.f};

    int srow = t >> 2, scg = (t & 3) * 8;
    for (int k0 = 0; k0 < K; k0 += 32) {
        __syncthreads();
        *(uint4*)&As[srow][scg]      = *(const uint4*)(A  + (size_t)(m0 + srow) * K + k0 + scg);
        *(uint4*)&As[srow + 64][scg] = *(const uint4*)(A  + (size_t)(m0 + srow + 64) * K + k0 + scg);
        *(uint4*)&Bs[srow][scg]      = *(const uint4*)(Bw + (size_t)(n0 + srow) * K + k0 + scg);
        *(uint4*)&Bs[srow + 64][scg] = *(const uint4*)(Bw + (size_t)(n0 + srow + 64) * K + k0 + scg);
        __syncthreads();
        bf16x8 af[4], bfr[4];
#pragma unroll
        for (int i = 0; i < 4; i++) {
            af[i]  = ld8(&As[wm + i * 16 + l16][quad * 8]);
            bfr[i] = ld8(&Bs[wn + i * 16 + l16][quad * 8]);
        }
#pragma unroll
        for (int i = 0; i < 4; i++)
#pragma unroll
            for (int j = 0; j < 4; j++)
                acc[i][j] = __builtin_amdgcn_mfma_f32_16x16x32_bf16(af[i], bfr[j], acc[i][j], 0, 0, 0);
    }
    // epilogue: D row = quad*4+r, col = l16 (m89-verified C/D layout)
#pragma unroll
    for (int i = 0; i < 4; i++)
#pragma unroll
        for (int j = 0; j < 4; j++) {
            int col = n0 + wn + j * 16 + l16;
            float bv = bias[col];
#pragma unroll
            for (int r = 0; r < 4; r++) {
                int row = m0 + wm + i * 16 + quad * 4 + r;
                Cp[(size_t)row * O3 + col] = f2bf(acc[i][j][r] + bv);
            }
        }
}

// proj: out[b][o][s] (fp32) = x[b][o][s] + sum_c proj_w[o][c] * o_t[b][s][c] + proj_b[o]
__global__ __launch_bounds__(256) void gemm_proj(const unsigned short* __restrict__ Pw,
                                                 const unsigned short* __restrict__ Oall,
                                                 const float* __restrict__ bias,
                                                 const float* __restrict__ xres,
                                                 float* __restrict__ Out) {
    const int K = 512;
    int bz = blockIdx.z;
    const unsigned short* Bv = Oall + (size_t)bz * SSP * CCH;
    int m0 = blockIdx.x * 128, n0 = blockIdx.y * 128;   // m = o, n = s

    __shared__ unsigned short As[128][40], Bs[128][40];
    int t = threadIdx.x, wave = t >> 6, lane = t & 63;
    int quad = lane >> 4, l16 = lane & 15;
    int wm = (wave & 1) * 64, wn = (wave >> 1) * 64;

    f32x4 acc[4][4];
#pragma unroll
    for (int i = 0; i < 4; i++)
#pragma unroll
        for (int j = 0; j < 4; j++) acc[i][j] = f32x4{0.f, 0.f, 0.f, 0.f};

    int srow = t >> 2, scg = (t & 3) * 8;
    for (int k0 = 0; k0 < K; k0 += 32) {
        __syncthreads();
        *(uint4*)&As[srow][scg]      = *(const uint4*)(Pw + (size_t)(m0 + srow) * K + k0 + scg);
        *(uint4*)&As[srow + 64][scg] = *(const uint4*)(Pw + (size_t)(m0 + srow + 64) * K + k0 + scg);
        *(uint4*)&Bs[srow][scg]      = *(const uint4*)(Bv + (size_t)(n0 + srow) * K + k0 + scg);
        *(uint4*)&Bs[srow + 64][scg] = *(const uint4*)(Bv + (size_t)(n0 + srow + 64) * K + k0 + scg);
        __syncthreads();
        bf16x8 af[4], bfr[4];
#pragma unroll
        for (int i = 0; i < 4; i++) {
            af[i]  = ld8(&As[wm + i * 16 + l16][quad * 8]);
            bfr[i] = ld8(&Bs[wn + i * 16 + l16][quad * 8]);
        }
#pragma unroll
        for (int i = 0; i < 4; i++)
#pragma unroll
            for (int j = 0; j < 4; j++)
                acc[i][j] = __builtin_amdgcn_mfma_f32_16x16x32_bf16(af[i], bfr[j], acc[i][j], 0, 0, 0);
    }
#pragma unroll
    for (int i = 0; i < 4; i++)
#pragma unroll
        for (int j = 0; j < 4; j++) {
            int col = n0 + wn + j * 16 + l16;          // s
#pragma unroll
            for (int r = 0; r < 4; r++) {
                int row = m0 + wm + i * 16 + quad * 4 + r;  // o
                size_t idx = (size_t)bz * CCH * SSP + (size_t)row * SSP + col;
                Out[idx] = xres[idx] + acc[i][j][r] + bias[row];
            }
        }
}

// ---------------------------------------------------------------------------
// V transpose: v_t[bh][c][j] = qkv_t[b][j][2C + h*64 + c]
__global__ __launch_bounds__(256) void vtrans(const unsigned short* __restrict__ qkvt,
                                              unsigned short* __restrict__ vt) {
    int j0 = blockIdx.x * 64;
    int bh = blockIdx.y;
    int b = bh >> 3, h = bh & 7;
    __shared__ unsigned short tl[64][72];
    int t = threadIdx.x;
#pragma unroll
    for (int p = 0; p < 2; p++) {
        int jr = p * 32 + (t >> 3), c8 = (t & 7) * 8;
        *(uint4*)&tl[jr][c8] =
            *(const uint4*)(qkvt + ((size_t)b * SSP + j0 + jr) * O3 + 2 * CCH + h * DH + c8);
    }
    __syncthreads();
#pragma unroll
    for (int p = 0; p < 2; p++) {
        int cr = p * 32 + (t >> 3), j8 = (t & 7) * 8;
        unsigned short vv[8];
#pragma unroll
        for (int i = 0; i < 8; i++) vv[i] = tl[j8 + i][cr];
        uint4 pack;
        pack.x = (unsigned)vv[0] | ((unsigned)vv[1] << 16);
        pack.y = (unsigned)vv[2] | ((unsigned)vv[3] << 16);
        pack.z = (unsigned)vv[4] | ((unsigned)vv[5] << 16);
        pack.w = (unsigned)vv[6] | ((unsigned)vv[7] << 16);
        *(uint4*)(vt + ((size_t)bh * DH + cr) * SSP + j0 + j8) = pack;
    }
}

// ---------------------------------------------------------------------------
// Flash attention: block = (b, h, 64 q-rows); 4 waves x 16 rows each.
// Per wave: scores 16x128 per j-block, wave-private online softmax, PV MFMA.
__global__ __launch_bounds__(256) void attn(const unsigned short* __restrict__ qkvt,
                                            const unsigned short* __restrict__ vt,
                                            unsigned short* __restrict__ ot) {
    int i0 = blockIdx.x * 64;
    int bh = blockIdx.y;
    int b = bh >> 3, h = bh & 7;

    __shared__ unsigned short Ks[128][72];      // [j][c]
    __shared__ unsigned short Vs[64][136];      // [c][j]
    __shared__ unsigned short Ps[4][16][136];   // per-wave [i][j]

    int t = threadIdx.x, wave = t >> 6, lane = t & 63;
    int quad = lane >> 4, l16 = lane & 15;
    const float c1 = 0.125f * 1.44269504f;      // scale * log2(e)

    // preload Q fragments (A-operand): rows i = i0 + wave*16 + l16
    bf16x8 qf[2];
    {
        const unsigned short* qp =
            qkvt + ((size_t)b * SSP + i0 + wave * 16 + l16) * O3 + h * DH + quad * 8;
        qf[0] = ld8(qp);
        qf[1] = ld8(qp + 32);
    }

    f32x4 Oa[4];
#pragma unroll
    for (int i = 0; i < 4; i++) Oa[i] = f32x4{0.f, 0.f, 0.f, 0.f};
    float m_run[4], l_run[4];
#pragma unroll
    for (int r = 0; r < 4; r++) { m_run[r] = -INFINITY; l_run[r] = 0.f; }

    for (int jb = 0; jb < 8; jb++) {
        int j0 = jb * 128;
        __syncthreads();
        // stage K tile [128 j][64 c]
#pragma unroll
        for (int p = 0; p < 4; p++) {
            int jr = p * 32 + (t >> 3), c8 = (t & 7) * 8;
            *(uint4*)&Ks[jr][c8] =
                *(const uint4*)(qkvt + ((size_t)b * SSP + j0 + jr) * O3 + CCH + h * DH + c8);
        }
        // stage V tile [64 c][128 j]
#pragma unroll
        for (int p = 0; p < 4; p++) {
            int cr = p * 16 + (t >> 4), j8 = (t & 15) * 8;
            *(uint4*)&Vs[cr][j8] =
                *(const uint4*)(vt + ((size_t)bh * DH + cr) * SSP + j0 + j8);
        }
        __syncthreads();

        // QK^T: D[16 i][128 j] per wave
        f32x4 sc[8];
#pragma unroll
        for (int tj = 0; tj < 8; tj++) sc[tj] = f32x4{0.f, 0.f, 0.f, 0.f};
#pragma unroll
        for (int kc = 0; kc < 2; kc++)
#pragma unroll
            for (int tj = 0; tj < 8; tj++) {
                bf16x8 kf = ld8(&Ks[tj * 16 + l16][kc * 32 + quad * 8]);
                sc[tj] = __builtin_amdgcn_mfma_f32_16x16x32_bf16(qf[kc], kf, sc[tj], 0, 0, 0);
            }

        // online softmax (rows quad*4+r, cols over l16 x 8 tiles)
        float rmax[4], rsum[4], alpha[4];
#pragma unroll
        for (int r = 0; r < 4; r++) {
            float m = sc[0][r];
#pragma unroll
            for (int tj = 1; tj < 8; tj++) m = fmaxf(m, sc[tj][r]);
#pragma unroll
            for (int o = 1; o < 16; o <<= 1) m = fmaxf(m, __shfl_xor(m, o, 64));
            float mn = fmaxf(m_run[r], m);
            alpha[r] = exp2f(c1 * (m_run[r] - mn));
            m_run[r] = mn;
            rsum[r] = 0.f;
        }
#pragma unroll
        for (int tj = 0; tj < 8; tj++)
#pragma unroll
            for (int r = 0; r < 4; r++) {
                float p = exp2f(c1 * (sc[tj][r] - m_run[r]));
                sc[tj][r] = p;
                rsum[r] += p;
            }
#pragma unroll
        for (int r = 0; r < 4; r++) {
#pragma unroll
            for (int o = 1; o < 16; o <<= 1) rsum[r] += __shfl_xor(rsum[r], o, 64);
            l_run[r] = l_run[r] * alpha[r] + rsum[r];
        }
        // write P (bf16) to wave-private LDS in [i][j] layout
#pragma unroll
        for (int tj = 0; tj < 8; tj++)
#pragma unroll
            for (int r = 0; r < 4; r++)
                Ps[wave][quad * 4 + r][tj * 16 + l16] = f2bf(sc[tj][r]);
        __syncthreads();   // cross-lane LDS visibility (cheap, safe)

        // rescale O, then PV accumulate
#pragma unroll
        for (int tc = 0; tc < 4; tc++)
#pragma unroll
            for (int r = 0; r < 4; r++) Oa[tc][r] *= alpha[r];
#pragma unroll
        for (int kj = 0; kj < 4; kj++) {
            bf16x8 pf = ld8(&Ps[wave][l16][kj * 32 + quad * 8]);
#pragma unroll
            for (int tc = 0; tc < 4; tc++) {
                bf16x8 vf = ld8(&Vs[tc * 16 + l16][kj * 32 + quad * 8]);
                Oa[tc] = __builtin_amdgcn_mfma_f32_16x16x32_bf16(pf, vf, Oa[tc], 0, 0, 0);
            }
        }
    }

    // finalize: divide by l, write o_t[b][i][h*64+c] bf16
    float rl[4];
#pragma unroll
    for (int r = 0; r < 4; r++) rl[r] = 1.f / l_run[r];
#pragma unroll
    for (int tc = 0; tc < 4; tc++)
#pragma unroll
        for (int r = 0; r < 4; r++) {
            int i = i0 + wave * 16 + quad * 4 + r;
            int c = tc * 16 + l16;
            ot[((size_t)b * SSP + i) * CCH + h * DH + c] = f2bf(Oa[tc][r] * rl[r]);
        }
}

// ---------------------------------------------------------------------------
extern "C" void kernel_launch(void* const* d_in, const int* in_sizes, int n_in,
                              void* d_out, int out_size, void* d_ws, size_t ws_size,
                              hipStream_t stream) {
    const float* x      = (const float*)d_in[0];
    const float* gn_w   = (const float*)d_in[1];
    const float* gn_b   = (const float*)d_in[2];
    const float* qkv_w  = (const float*)d_in[3];
    const float* qkv_b  = (const float*)d_in[4];
    const float* proj_w = (const float*)d_in[5];
    const float* proj_b = (const float*)d_in[6];
    float* out = (float*)d_out;

    char* ws = (char*)d_ws;
    // workspace layout (50 MB total)
    unsigned short* xnt   = (unsigned short*)(ws);                 // 8 MB  xn_t[b][s][c]
    unsigned short* qw_bf = (unsigned short*)(ws + 8388608);       // 1.5MB qkv_w bf16
    unsigned short* pw_bf = (unsigned short*)(ws + 9961472);       // 0.5MB proj_w bf16
    unsigned short* qkvt  = (unsigned short*)(ws + 10485760);      // 24 MB qkv_t[b][s][3C]
    unsigned short* vt    = (unsigned short*)(ws + 35651584);      // 8 MB  v_t[bh][c][j]
    unsigned short* otb   = (unsigned short*)(ws + 44040192);      // 8 MB  o_t[b][s][c]

    wconv<<<dim3(768), dim3(256), 0, stream>>>(qkv_w, qw_bf, 786432 / 4);
    wconv<<<dim3(256), dim3(256), 0, stream>>>(proj_w, pw_bf, 262144 / 4);
    groupnorm_t<<<dim3(256), dim3(256), 0, stream>>>(x, gn_w, gn_b, xnt);
    gemm_qkv<<<dim3(8, 12, 8), dim3(256), 0, stream>>>(xnt, qw_bf, qkv_b, qkvt);
    vtrans<<<dim3(16, 64), dim3(256), 0, stream>>>(qkvt, vt);
    attn<<<dim3(16, 64), dim3(256), 0, stream>>>(qkvt, vt, otb);
    gemm_proj<<<dim3(4, 8, 8), dim3(256), 0, stream>>>(pw_bf, otb, proj_b, x, out);
}

// Round 2
// 177.762 us; speedup vs baseline: 1.2920x; 1.2920x over previous
//
#include <hip/hip_runtime.h>
#include <cstdint>
#include <cstddef>

// Problem constants
#define BATCH 8
#define CCH   512     // channels
#define SSP   1024    // spatial = 32*32
#define NH    8       // heads
#define DH    64      // head dim
#define O3    1536    // 3*C

typedef __bf16 bf16x8 __attribute__((ext_vector_type(8)));
typedef float  f32x4  __attribute__((ext_vector_type(4)));

__device__ __forceinline__ unsigned short f2bf(float f) {
    unsigned u = __builtin_bit_cast(unsigned, f);
    unsigned r = u + 0x7fffu + ((u >> 16) & 1u);   // RNE
    return (unsigned short)(r >> 16);
}

// pack two fp32 -> one dword of 2 bf16 (round-half-up), single v_perm
__device__ __forceinline__ unsigned pk2bf(float lo, float hi) {
    unsigned ul = __builtin_bit_cast(unsigned, lo) + 0x8000u;
    unsigned uh = __builtin_bit_cast(unsigned, hi) + 0x8000u;
    return __builtin_amdgcn_perm(uh, ul, 0x07060302u);  // [ul.b2,ul.b3,uh.b2,uh.b3]
}

__device__ __forceinline__ bf16x8 ld8(const unsigned short* p) {
    uint4 u = *(const uint4*)p;
    return __builtin_bit_cast(bf16x8, u);
}

// ---------------------------------------------------------------------------
// fp32 -> bf16 weight conversion (qkv_w, proj_w)
__global__ __launch_bounds__(256) void wconv(const float* __restrict__ src,
                                             unsigned short* __restrict__ dst,
                                             int n4) {
    int i = blockIdx.x * 256 + threadIdx.x;
    if (i < n4) {
        float4 v = ((const float4*)src)[i];
        ushort4 o;
        o.x = f2bf(v.x); o.y = f2bf(v.y); o.z = f2bf(v.z); o.w = f2bf(v.w);
        ((ushort4*)dst)[i] = o;
    }
}

// ---------------------------------------------------------------------------
// GroupNorm (32 groups) + transpose write: xn_t[b][s][c] in bf16.
__global__ __launch_bounds__(256) void groupnorm_t(const float* __restrict__ x,
                                                   const float* __restrict__ gw,
                                                   const float* __restrict__ gb,
                                                   unsigned short* __restrict__ xnt) {
    int blk = blockIdx.x;
    int b = blk >> 5, g = blk & 31;
    const float4* xp = (const float4*)(x + (size_t)(b * CCH + g * 16) * SSP);
    int t = threadIdx.x;

    float4 vals[16];
    float sum = 0.f, ss = 0.f;
#pragma unroll
    for (int i = 0; i < 16; i++) {
        float4 v = xp[i * 256 + t];
        vals[i] = v;
        sum += (v.x + v.y) + (v.z + v.w);
        ss  += (v.x * v.x + v.y * v.y) + (v.z * v.z + v.w * v.w);
    }
#pragma unroll
    for (int o = 32; o; o >>= 1) {
        sum += __shfl_xor(sum, o, 64);
        ss  += __shfl_xor(ss,  o, 64);
    }
    __shared__ float red[8];
    if ((t & 63) == 0) { red[(t >> 6) * 2] = sum; red[(t >> 6) * 2 + 1] = ss; }
    __syncthreads();
    sum = red[0] + red[2] + red[4] + red[6];
    ss  = red[1] + red[3] + red[5] + red[7];

    float mean = sum * (1.f / 16384.f);
    float var  = ss * (1.f / 16384.f) - mean * mean;
    float rstd = rsqrtf(var + 1e-5f);

    __shared__ unsigned short tile[16][1032];
#pragma unroll
    for (int i = 0; i < 16; i++) {
        int f4 = i * 256 + t;
        int c = f4 >> 8;
        int s = (f4 & 255) * 4;
        float wsc = gw[g * 16 + c] * rstd;
        float bia = gb[g * 16 + c] - mean * wsc;
        float4 v = vals[i];
        tile[c][s + 0] = f2bf(v.x * wsc + bia);
        tile[c][s + 1] = f2bf(v.y * wsc + bia);
        tile[c][s + 2] = f2bf(v.z * wsc + bia);
        tile[c][s + 3] = f2bf(v.w * wsc + bia);
    }
    __syncthreads();

    int c2 = (t & 7) * 2, sr = t >> 3;
    unsigned short* outbase = xnt + (size_t)b * SSP * CCH + g * 16 + c2;
#pragma unroll
    for (int i = 0; i < 32; i++) {
        int s = i * 32 + sr;
        unsigned v = (unsigned)tile[c2][s] | ((unsigned)tile[c2 + 1][s] << 16);
        *(unsigned*)(outbase + (size_t)s * CCH) = v;
    }
}

// ---------------------------------------------------------------------------
// NT GEMM 128x128 tile, 16x16x32 bf16 MFMA, K=512.
__global__ __launch_bounds__(256) void gemm_qkv(const unsigned short* __restrict__ Aall,
                                                const unsigned short* __restrict__ Bw,
                                                const float* __restrict__ bias,
                                                unsigned short* __restrict__ Call) {
    const int K = 512;
    int bz = blockIdx.z;
    const unsigned short* A = Aall + (size_t)bz * SSP * CCH;
    unsigned short* Cp = Call + (size_t)bz * SSP * O3;
    int m0 = blockIdx.x * 128, n0 = blockIdx.y * 128;

    __shared__ unsigned short As[128][40], Bs[128][40];
    int t = threadIdx.x, wave = t >> 6, lane = t & 63;
    int quad = lane >> 4, l16 = lane & 15;
    int wm = (wave & 1) * 64, wn = (wave >> 1) * 64;

    f32x4 acc[4][4];
#pragma unroll
    for (int i = 0; i < 4; i++)
#pragma unroll
        for (int j = 0; j < 4; j++) acc[i][j] = f32x4{0.f, 0.f, 0.f, 0.f};

    int srow = t >> 2, scg = (t & 3) * 8;
    for (int k0 = 0; k0 < K; k0 += 32) {
        __syncthreads();
        *(uint4*)&As[srow][scg]      = *(const uint4*)(A  + (size_t)(m0 + srow) * K + k0 + scg);
        *(uint4*)&As[srow + 64][scg] = *(const uint4*)(A  + (size_t)(m0 + srow + 64) * K + k0 + scg);
        *(uint4*)&Bs[srow][scg]      = *(const uint4*)(Bw + (size_t)(n0 + srow) * K + k0 + scg);
        *(uint4*)&Bs[srow + 64][scg] = *(const uint4*)(Bw + (size_t)(n0 + srow + 64) * K + k0 + scg);
        __syncthreads();
        bf16x8 af[4], bfr[4];
#pragma unroll
        for (int i = 0; i < 4; i++) {
            af[i]  = ld8(&As[wm + i * 16 + l16][quad * 8]);
            bfr[i] = ld8(&Bs[wn + i * 16 + l16][quad * 8]);
        }
#pragma unroll
        for (int i = 0; i < 4; i++)
#pragma unroll
            for (int j = 0; j < 4; j++)
                acc[i][j] = __builtin_amdgcn_mfma_f32_16x16x32_bf16(af[i], bfr[j], acc[i][j], 0, 0, 0);
    }
#pragma unroll
    for (int i = 0; i < 4; i++)
#pragma unroll
        for (int j = 0; j < 4; j++) {
            int col = n0 + wn + j * 16 + l16;
            float bv = bias[col];
#pragma unroll
            for (int r = 0; r < 4; r++) {
                int row = m0 + wm + i * 16 + quad * 4 + r;
                Cp[(size_t)row * O3 + col] = f2bf(acc[i][j][r] + bv);
            }
        }
}

// proj: out[b][o][s] (fp32) = x[b][o][s] + sum_c proj_w[o][c] * o_t[b][s][c] + proj_b[o]
__global__ __launch_bounds__(256) void gemm_proj(const unsigned short* __restrict__ Pw,
                                                 const unsigned short* __restrict__ Oall,
                                                 const float* __restrict__ bias,
                                                 const float* __restrict__ xres,
                                                 float* __restrict__ Out) {
    const int K = 512;
    int bz = blockIdx.z;
    const unsigned short* Bv = Oall + (size_t)bz * SSP * CCH;
    int m0 = blockIdx.x * 128, n0 = blockIdx.y * 128;

    __shared__ unsigned short As[128][40], Bs[128][40];
    int t = threadIdx.x, wave = t >> 6, lane = t & 63;
    int quad = lane >> 4, l16 = lane & 15;
    int wm = (wave & 1) * 64, wn = (wave >> 1) * 64;

    f32x4 acc[4][4];
#pragma unroll
    for (int i = 0; i < 4; i++)
#pragma unroll
        for (int j = 0; j < 4; j++) acc[i][j] = f32x4{0.f, 0.f, 0.f, 0.f};

    int srow = t >> 2, scg = (t & 3) * 8;
    for (int k0 = 0; k0 < K; k0 += 32) {
        __syncthreads();
        *(uint4*)&As[srow][scg]      = *(const uint4*)(Pw + (size_t)(m0 + srow) * K + k0 + scg);
        *(uint4*)&As[srow + 64][scg] = *(const uint4*)(Pw + (size_t)(m0 + srow + 64) * K + k0 + scg);
        *(uint4*)&Bs[srow][scg]      = *(const uint4*)(Bv + (size_t)(n0 + srow) * K + k0 + scg);
        *(uint4*)&Bs[srow + 64][scg] = *(const uint4*)(Bv + (size_t)(n0 + srow + 64) * K + k0 + scg);
        __syncthreads();
        bf16x8 af[4], bfr[4];
#pragma unroll
        for (int i = 0; i < 4; i++) {
            af[i]  = ld8(&As[wm + i * 16 + l16][quad * 8]);
            bfr[i] = ld8(&Bs[wn + i * 16 + l16][quad * 8]);
        }
#pragma unroll
        for (int i = 0; i < 4; i++)
#pragma unroll
            for (int j = 0; j < 4; j++)
                acc[i][j] = __builtin_amdgcn_mfma_f32_16x16x32_bf16(af[i], bfr[j], acc[i][j], 0, 0, 0);
    }
#pragma unroll
    for (int i = 0; i < 4; i++)
#pragma unroll
        for (int j = 0; j < 4; j++) {
            int col = n0 + wn + j * 16 + l16;
#pragma unroll
            for (int r = 0; r < 4; r++) {
                int row = m0 + wm + i * 16 + quad * 4 + r;
                size_t idx = (size_t)bz * CCH * SSP + (size_t)row * SSP + col;
                Out[idx] = xres[idx] + acc[i][j][r] + bias[row];
            }
        }
}

// ---------------------------------------------------------------------------
// V transpose: v_t[bh][c][j] = qkv_t[b][j][2C + h*64 + c]
__global__ __launch_bounds__(256) void vtrans(const unsigned short* __restrict__ qkvt,
                                              unsigned short* __restrict__ vt) {
    int j0 = blockIdx.x * 64;
    int bh = blockIdx.y;
    int b = bh >> 3, h = bh & 7;
    __shared__ unsigned short tl[64][72];
    int t = threadIdx.x;
#pragma unroll
    for (int p = 0; p < 2; p++) {
        int jr = p * 32 + (t >> 3), c8 = (t & 7) * 8;
        *(uint4*)&tl[jr][c8] =
            *(const uint4*)(qkvt + ((size_t)b * SSP + j0 + jr) * O3 + 2 * CCH + h * DH + c8);
    }
    __syncthreads();
#pragma unroll
    for (int p = 0; p < 2; p++) {
        int cr = p * 32 + (t >> 3), j8 = (t & 7) * 8;
        unsigned short vv[8];
#pragma unroll
        for (int i = 0; i < 8; i++) vv[i] = tl[j8 + i][cr];
        uint4 pack;
        pack.x = (unsigned)vv[0] | ((unsigned)vv[1] << 16);
        pack.y = (unsigned)vv[2] | ((unsigned)vv[3] << 16);
        pack.z = (unsigned)vv[4] | ((unsigned)vv[5] << 16);
        pack.w = (unsigned)vv[6] | ((unsigned)vv[7] << 16);
        *(uint4*)(vt + ((size_t)bh * DH + cr) * SSP + j0 + j8) = pack;
    }
}

// ---------------------------------------------------------------------------
// Flash attention v2 — fully transposed: S^T = K·Q^T so softmax rows are
// lane-aligned (col=lane&15 = i). P^T packed to per-wave LDS (aliases Ks),
// O^T = V^T·P^T so alpha/l are scalar per lane.
__global__ __launch_bounds__(256, 4) void attn(const unsigned short* __restrict__ qkvt,
                                               const unsigned short* __restrict__ vt,
                                               unsigned short* __restrict__ ot) {
    int i0 = blockIdx.x * 64;
    int bh = blockIdx.y;
    int b = bh >> 3, h = bh & 7;

    __shared__ unsigned short Ks[128][72];   // [j][c]; aliased as P^T store during PV
    __shared__ unsigned short Vs[64][136];   // [c][j]

    int t = threadIdx.x, wave = t >> 6, lane = t & 63;
    int quad = lane >> 4, l16 = lane & 15;
    const float c1 = 0.125f * 1.44269504f;   // scale * log2(e)

    // per-wave P region inside Ks (Ks: 9216 shorts >= 4*16*136 = 8704)
    unsigned short* Ps = &Ks[0][0] + wave * (16 * 136);

    // Q fragment (B-operand): lane n = l16 = local i, k = c contiguous
    bf16x8 qf[2];
    {
        const unsigned short* qp =
            qkvt + ((size_t)b * SSP + i0 + wave * 16 + l16) * O3 + h * DH + quad * 8;
        qf[0] = ld8(qp);
        qf[1] = ld8(qp + 32);
    }

    f32x4 Oa[4];
#pragma unroll
    for (int i = 0; i < 4; i++) Oa[i] = f32x4{0.f, 0.f, 0.f, 0.f};
    float m_run = -INFINITY, l_run = 0.f;

    int jr = t >> 3, c8 = (t & 7) * 8;       // K staging coords
    int cr = t >> 4, j8 = (t & 15) * 8;      // V staging coords

    for (int jb = 0; jb < 8; jb++) {
        int j0 = jb * 128;
        __syncthreads();   // protects prev-iter P reads (Ks region) + Vs reads
#pragma unroll
        for (int p = 0; p < 4; p++) {
            int row = p * 32 + jr;
            *(uint4*)&Ks[row][c8] =
                *(const uint4*)(qkvt + ((size_t)b * SSP + j0 + row) * O3 + CCH + h * DH + c8);
        }
#pragma unroll
        for (int p = 0; p < 4; p++) {
            *(uint4*)&Vs[p * 16 + cr][j8] =
                *(const uint4*)(vt + ((size_t)bh * DH + p * 16 + cr) * SSP + j0 + j8);
        }
        __syncthreads();

        // S^T: D[m=j][n=i]; A = K rows (k-contig), B = Q
        f32x4 sc[8];
#pragma unroll
        for (int tj = 0; tj < 8; tj++) sc[tj] = f32x4{0.f, 0.f, 0.f, 0.f};
#pragma unroll
        for (int kc = 0; kc < 2; kc++)
#pragma unroll
            for (int tj = 0; tj < 8; tj++) {
                bf16x8 kf = ld8(&Ks[tj * 16 + l16][kc * 32 + quad * 8]);
                sc[tj] = __builtin_amdgcn_mfma_f32_16x16x32_bf16(kf, qf[kc], sc[tj], 0, 0, 0);
            }

        // lane-aligned online softmax: lane owns row i = l16, j = tj*16+quad*4+r
        float m = sc[0][0];
#pragma unroll
        for (int tj = 0; tj < 8; tj++)
#pragma unroll
            for (int r = 0; r < 4; r++) m = fmaxf(m, sc[tj][r]);
        m = fmaxf(m, __shfl_xor(m, 16, 64));
        m = fmaxf(m, __shfl_xor(m, 32, 64));
        float mn = fmaxf(m_run, m);
        float alpha = __builtin_amdgcn_exp2f(c1 * (m_run - mn));
        m_run = mn;
        float cm = c1 * mn;
        float rs = 0.f;
#pragma unroll
        for (int tj = 0; tj < 8; tj++)
#pragma unroll
            for (int r = 0; r < 4; r++) {
                float p = __builtin_amdgcn_exp2f(c1 * sc[tj][r] - cm);
                sc[tj][r] = p;
                rs += p;
            }
        rs += __shfl_xor(rs, 16, 64);
        rs += __shfl_xor(rs, 32, 64);
        l_run = l_run * alpha + rs;

        __syncthreads();   // all waves done reading Ks before P overwrites it

        // pack P^T rows: Ps[i=l16][j], 4 consecutive j per 8B write
#pragma unroll
        for (int tj = 0; tj < 8; tj++) {
            uint2 d;
            d.x = pk2bf(sc[tj][0], sc[tj][1]);
            d.y = pk2bf(sc[tj][2], sc[tj][3]);
            *(uint2*)&Ps[l16 * 136 + tj * 16 + quad * 4] = d;
        }

        // O^T += V^T · P^T  (A = V^T: m=c; B = P^T: n=i); scalar rescale
#pragma unroll
        for (int tc = 0; tc < 4; tc++)
#pragma unroll
            for (int r = 0; r < 4; r++) Oa[tc][r] *= alpha;
#pragma unroll
        for (int kj = 0; kj < 4; kj++) {
            bf16x8 pf = ld8(&Ps[l16 * 136 + kj * 32 + quad * 8]);
#pragma unroll
            for (int tc = 0; tc < 4; tc++) {
                bf16x8 vf = ld8(&Vs[tc * 16 + l16][kj * 32 + quad * 8]);
                Oa[tc] = __builtin_amdgcn_mfma_f32_16x16x32_bf16(vf, pf, Oa[tc], 0, 0, 0);
            }
        }
    }

    // finalize: O^T[c][i]: row regs = c = tc*16+quad*4+r, col lane = i = l16
    float rl = 1.f / l_run;
    int i = i0 + wave * 16 + l16;
    unsigned short* ob = ot + ((size_t)b * SSP + i) * CCH + h * DH;
#pragma unroll
    for (int tc = 0; tc < 4; tc++) {
        uint2 d;
        d.x = pk2bf(Oa[tc][0] * rl, Oa[tc][1] * rl);
        d.y = pk2bf(Oa[tc][2] * rl, Oa[tc][3] * rl);
        *(uint2*)(ob + tc * 16 + quad * 4) = d;
    }
}

// ---------------------------------------------------------------------------
extern "C" void kernel_launch(void* const* d_in, const int* in_sizes, int n_in,
                              void* d_out, int out_size, void* d_ws, size_t ws_size,
                              hipStream_t stream) {
    const float* x      = (const float*)d_in[0];
    const float* gn_w   = (const float*)d_in[1];
    const float* gn_b   = (const float*)d_in[2];
    const float* qkv_w  = (const float*)d_in[3];
    const float* qkv_b  = (const float*)d_in[4];
    const float* proj_w = (const float*)d_in[5];
    const float* proj_b = (const float*)d_in[6];
    float* out = (float*)d_out;

    char* ws = (char*)d_ws;
    unsigned short* xnt   = (unsigned short*)(ws);                 // 8 MB
    unsigned short* qw_bf = (unsigned short*)(ws + 8388608);       // 1.5MB
    unsigned short* pw_bf = (unsigned short*)(ws + 9961472);       // 0.5MB
    unsigned short* qkvt  = (unsigned short*)(ws + 10485760);      // 24 MB
    unsigned short* vt    = (unsigned short*)(ws + 35651584);      // 8 MB
    unsigned short* otb   = (unsigned short*)(ws + 44040192);      // 8 MB

    wconv<<<dim3(768), dim3(256), 0, stream>>>(qkv_w, qw_bf, 786432 / 4);
    wconv<<<dim3(256), dim3(256), 0, stream>>>(proj_w, pw_bf, 262144 / 4);
    groupnorm_t<<<dim3(256), dim3(256), 0, stream>>>(x, gn_w, gn_b, xnt);
    gemm_qkv<<<dim3(8, 12, 8), dim3(256), 0, stream>>>(xnt, qw_bf, qkv_b, qkvt);
    vtrans<<<dim3(16, 64), dim3(256), 0, stream>>>(qkvt, vt);
    attn<<<dim3(16, 64), dim3(256), 0, stream>>>(qkvt, vt, otb);
    gemm_proj<<<dim3(4, 8, 8), dim3(256), 0, stream>>>(pw_bf, otb, proj_b, x, out);
}